// Round 7
// baseline (105.710 us; speedup 1.0000x reference)
//
#include <hip/hip_runtime.h>
#include <hip/hip_fp16.h>

constexpr int Bc  = 4;
constexpr int Cc  = 64;
constexpr int H0  = 128;
constexpr int W0  = 128;
constexpr int HW  = H0 * W0;
constexpr int Gc  = 4;
constexpr int CG  = Cc / Gc;     // 16
constexpr int HOc = H0 * 2;      // 256
constexpr int WOc = W0 * 2;      // 256

constexpr int TW = 16;           // output tile width
constexpr int TH = 8;            // output tile height
constexpr int HX = TW + 2;       // 18 halo cols
constexpr int HY = TH + 2;       // 10 halo rows
constexpr int NHALO = HX * HY;   // 180
constexpr int NTASK = Gc * NHALO;// 720

constexpr int SXC = 10;          // staged input cols (ox/2-1 .. ox/2+8)
constexpr int SYC = 6;           // staged input rows (oy/2-1 .. oy/2+4)
constexpr int SN  = SXC * SYC;   // 60 elems per channel

// ---------------------------------------------------------------------------
// kT: transpose offset weights into ws: wT[mat][c][r], mat 0=w_off 1=w_offm.
// 4096 elements, one-shot, ~negligible.
// ---------------------------------------------------------------------------
__global__ __launch_bounds__(256) void kT_transpose(
    const float* __restrict__ w_off, const float* __restrict__ w_offm,
    float* __restrict__ wT)
{
    const int i = blockIdx.x * 256 + threadIdx.x;    // 0..4095
    const int mat = i >> 11;
    const int rem = i & 2047;
    const int c   = rem >> 5;
    const int r   = rem & 31;
    wT[i] = (mat ? w_offm : w_off)[r * Cc + c];
}

// ---------------------------------------------------------------------------
// k0 v3: gated offset conv. Thread = 1 pixel, role-split (waves 0-1: w_off,
// waves 2-3: w_offm). Weights via wave-uniform s_load_dwordx4 from transposed
// wT (scalar pipe — no LDS issue cost). Sigmoid exchanged through tiny LDS.
// Output: half2 (offx,offy) per (b, pair, pixel), 4 MB total.
// ---------------------------------------------------------------------------
__global__ __launch_bounds__(256) void k0_offsets(
    const float* __restrict__ x, const float* __restrict__ wT,
    const float* __restrict__ b_off, const float* __restrict__ b_offm,
    __half2* __restrict__ offbuf)
{
    __shared__ float sig[128][33];      // sigmoid exchange, padded stride

    const int b    = blockIdx.y;
    const int t    = threadIdx.x;
    const int role = t >> 7;            // wave-uniform: 0 -> w_off, 1 -> w_offm
    const int pl   = t & 127;
    const int px   = blockIdx.x * 128 + pl;

    const float4* wt4 = reinterpret_cast<const float4*>(wT + role * 2048);

    float acc[32];
#pragma unroll
    for (int r = 0; r < 32; ++r) acc[r] = 0.f;

    const float* xp = x + (size_t)b * Cc * HW + px;
#pragma unroll 4
    for (int c = 0; c < Cc; ++c) {
        const float xv = xp[c * HW];                 // coalesced
#pragma unroll
        for (int q = 0; q < 8; ++q) {
            const float4 wv = wt4[c * 8 + q];        // uniform -> s_load_dwordx4
            acc[4 * q + 0] = fmaf(wv.x, xv, acc[4 * q + 0]);
            acc[4 * q + 1] = fmaf(wv.y, xv, acc[4 * q + 1]);
            acc[4 * q + 2] = fmaf(wv.z, xv, acc[4 * q + 2]);
            acc[4 * q + 3] = fmaf(wv.w, xv, acc[4 * q + 3]);
        }
    }

    if (role == 1) {
#pragma unroll
        for (int r = 0; r < 32; ++r)
            sig[pl][r] = 1.f / (1.f + __expf(-(acc[r] + b_offm[r])));
    }
    __syncthreads();

    if (role == 0) {
#pragma unroll
        for (int rp = 0; rp < 16; ++rp) {
            const float vx = (acc[2 * rp]     + b_off[2 * rp])     * sig[pl][2 * rp];
            const float vy = (acc[2 * rp + 1] + b_off[2 * rp + 1]) * sig[pl][2 * rp + 1];
            offbuf[((size_t)b * 16 + rp) * HW + px] = __floats2half2_rn(vx, vy);
        }
    }
}

// ---------------------------------------------------------------------------
// k1_fused: round-6 structure, xstage in fp16 -> LDS 31.5 KB -> 5 blocks/CU.
// NO block swizzle (round-5 lesson), default launch bounds.
// ---------------------------------------------------------------------------
__global__ __launch_bounds__(256) void k1_fused(
    const float* __restrict__ x, const __half2* __restrict__ offbuf,
    const float* __restrict__ w_sk, const float* __restrict__ b_sk,
    const float* __restrict__ w_km, const float* __restrict__ b_km,
    float* __restrict__ out)
{
    __shared__ __half xd[Cc][NHALO];      // 23040 B: deformed halo, fp16
    __shared__ float  ovl[2304];          //  9216 B: xstage(fp16) | kmb,sknb
    __half* xstage = (__half*)ovl;        // [c][60] halves (7680 B)
    float* kmb    = ovl;                  // [128][9]
    float* sknb   = ovl + 128 * 9;        // [128][9]

    const int b    = blockIdx.y;
    const int tile = blockIdx.x;          // 16 x-tiles * 32 y-tiles
    const int ox = (tile & 15) * TW;
    const int oy = (tile >> 4) * TH;
    const int t  = threadIdx.x;
    const int syr = (oy >> 1) - 1;        // staged window origin (input coords)
    const int sxr = (ox >> 1) - 1;

    const float* xb = x + (size_t)b * Cc * HW;

    // ---- phase A: stage 6x10 input window, 64 ch, fp16 (border-clamped) ----
    for (int i = t; i < Cc * SN; i += 256) {          // 15 iters
        const int c   = i / SN;
        const int rem = i - c * SN;
        const int r   = rem / SXC;
        const int j   = rem - r * SXC;
        const int yy  = min(max(syr + r, 0), H0 - 1);
        const int xx  = min(max(sxr + j, 0), W0 - 1);
        xstage[i] = __float2half(xb[(size_t)c * HW + yy * W0 + xx]);
    }
    __syncthreads();

    // ---- phase B: bilinear sample halo -> xd (fp16), offsets via half2 ----
    for (int task = t; task < NTASK; task += 256) {
        const int g   = task / NHALO;
        const int pix = task - g * NHALO;
        const int hy  = pix / HX;
        const int hx  = pix - hy * HX;
        const int gy  = oy - 1 + hy;
        const int gx  = ox - 1 + hx;
        if (gy < 0 || gy >= HOc || gx < 0 || gx >= WOc) {
#pragma unroll 4
            for (int c = 0; c < CG; ++c) xd[g * CG + c][pix] = __half(0.f);
            continue;
        }
        const int sy = gy & 1, sx = gx & 1;
        const int h  = gy >> 1, w  = gx >> 1;
        const __half2 o2 = offbuf[((size_t)b * 16 + g * 4 + sy * 2 + sx) * HW
                                  + h * W0 + w];
        const float offx = __low2float(o2);
        const float offy = __high2float(o2);

        float ix = ((float)gx + 0.5f + offx) * 0.5f - 0.5f;
        float iy = ((float)gy + 0.5f + offy) * 0.5f - 0.5f;
        ix = fminf(fmaxf(ix, 0.f), (float)(W0 - 1));
        iy = fminf(fmaxf(iy, 0.f), (float)(H0 - 1));
        const float x0f = floorf(ix), y0f = floorf(iy);
        const float wx = ix - x0f,   wy = iy - y0f;
        const int x0 = (int)x0f, y0 = (int)y0f;
        const int x1 = min(x0 + 1, W0 - 1), y1 = min(y0 + 1, H0 - 1);
        const float w00 = (1.f - wx) * (1.f - wy);
        const float w01 = wx * (1.f - wy);
        const float w10 = (1.f - wx) * wy;
        const float w11 = wx * wy;

        const int j0 = x0 - sxr, j1 = x1 - sxr;
        const int i0 = y0 - syr, i1 = y1 - syr;
        const bool inl = (j0 >= 0) & (j1 < SXC) & (i0 >= 0) & (i1 < SYC);

        if (inl) {
            const int o00 = i0 * SXC + j0, o01 = i0 * SXC + j1;
            const int o10 = i1 * SXC + j0, o11 = i1 * SXC + j1;
            const __half* s = xstage + (g * CG) * SN;
#pragma unroll 4
            for (int c = 0; c < CG; ++c) {
                const __half* pc = s + c * SN;
                const float v = w00 * __half2float(pc[o00])
                              + w01 * __half2float(pc[o01])
                              + w10 * __half2float(pc[o10])
                              + w11 * __half2float(pc[o11]);
                xd[g * CG + c][pix] = __float2half(v);
            }
        } else {  // rare: tap escaped staged window -> global
            const int o00 = y0 * W0 + x0, o01 = y0 * W0 + x1;
            const int o10 = y1 * W0 + x0, o11 = y1 * W0 + x1;
            const float* xg = xb + (size_t)(g * CG) * HW;
#pragma unroll 4
            for (int c = 0; c < CG; ++c) {
                const float* pc = xg + (size_t)c * HW;
                const float v = w00 * pc[o00] + w01 * pc[o01]
                              + w10 * pc[o10] + w11 * pc[o11];
                xd[g * CG + c][pix] = __float2half(v);
            }
        }
    }
    __syncthreads();

    // ---- phase C: sk/km dots (wave-split), gate + softmax -> sknb ----
    {
        const int p   = t & 127;
        const int ctr = ((p >> 4) + 1) * HX + (p & 15) + 1;
        float acc[9];
#pragma unroll
        for (int k = 0; k < 9; ++k) acc[k] = 0.f;

        if (t < 128) {
            for (int c = 0; c < Cc; ++c) {
                const float xv = __half2float(xd[c][ctr]);
#pragma unroll
                for (int k = 0; k < 9; ++k)
                    acc[k] = fmaf(w_sk[k * Cc + c], xv, acc[k]);  // s_load
            }
        } else {
            for (int c = 0; c < Cc; ++c) {
                const float xv = __half2float(xd[c][ctr]);
#pragma unroll
                for (int k = 0; k < 9; ++k)
                    acc[k] = fmaf(w_km[k * Cc + c], xv, acc[k]);
            }
#pragma unroll
            for (int k = 0; k < 9; ++k) kmb[p * 9 + k] = acc[k];
        }
        __syncthreads();

        if (t < 128) {
            float sv[9], mx = -1e30f;
#pragma unroll
            for (int k = 0; k < 9; ++k) {
                const float z = kmb[p * 9 + k] + b_km[k];
                sv[k] = (acc[k] + b_sk[k]) / (1.f + __expf(-z));
                mx = fmaxf(mx, sv[k]);
            }
            float sum = 0.f;
#pragma unroll
            for (int k = 0; k < 9; ++k) { sv[k] = __expf(sv[k] - mx); sum += sv[k]; }
            const float inv = 1.f / sum;
#pragma unroll
            for (int k = 0; k < 9; ++k) sknb[p * 9 + k] = sv[k] * inv;
        }
    }
    __syncthreads();

    // ---- phase D: 3x3 dynamic conv, 2x2 pixel register blocking ----
    {
        const int sq    = t & 31;         // 8x4 squares of 2x2 pixels
        const int chunk = t >> 5;         // 8 channel chunks
        const int sqx = sq & 7, sqy = sq >> 3;
        const int hx0 = 2 * sqx, hy0 = 2 * sqy;
        const int p00 = (2 * sqy) * TW + 2 * sqx;

        float s00[9], s01[9], s10[9], s11[9];
#pragma unroll
        for (int k = 0; k < 9; ++k) {
            s00[k] = sknb[p00 * 9 + k];        s01[k] = sknb[(p00 + 1) * 9 + k];
            s10[k] = sknb[(p00 + TW) * 9 + k]; s11[k] = sknb[(p00 + TW + 1) * 9 + k];
        }
        const int orow0 = oy + 2 * sqy, ocol0 = ox + 2 * sqx;

#pragma unroll 2
        for (int i = 0; i < 8; ++i) {
            const int c = chunk * 8 + i;
            const __half* xc = &xd[c][0];
            float wd[4][4];
#pragma unroll
            for (int ry = 0; ry < 4; ++ry) {
                const int base = (hy0 + ry) * HX + hx0;
                const __half2 u0 = *reinterpret_cast<const __half2*>(&xc[base]);
                const __half2 u1 = *reinterpret_cast<const __half2*>(&xc[base + 2]);
                const float2 f0 = __half22float2(u0);
                const float2 f1 = __half22float2(u1);
                wd[ry][0] = f0.x; wd[ry][1] = f0.y; wd[ry][2] = f1.x; wd[ry][3] = f1.y;
            }
            float a00 = 0.f, a01 = 0.f, a10 = 0.f, a11 = 0.f;
#pragma unroll
            for (int ky = 0; ky < 3; ++ky)
#pragma unroll
                for (int kx = 0; kx < 3; ++kx) {
                    const int k = ky * 3 + kx;
                    a00 = fmaf(s00[k], wd[ky    ][kx    ], a00);
                    a01 = fmaf(s01[k], wd[ky    ][kx + 1], a01);
                    a10 = fmaf(s10[k], wd[ky + 1][kx    ], a10);
                    a11 = fmaf(s11[k], wd[ky + 1][kx + 1], a11);
                }
            float* ob = out + ((size_t)(b * Cc + c)) * (HOc * WOc)
                            + (size_t)orow0 * WOc + ocol0;
            *reinterpret_cast<float2*>(ob)       = make_float2(a00, a01);
            *reinterpret_cast<float2*>(ob + WOc) = make_float2(a10, a11);
        }
    }
}

// ---------------------------------------------------------------------------
extern "C" void kernel_launch(void* const* d_in, const int* in_sizes, int n_in,
                              void* d_out, int out_size, void* d_ws, size_t ws_size,
                              hipStream_t stream)
{
    const float* x      = (const float*)d_in[0];
    const float* w_off  = (const float*)d_in[1];
    const float* b_off  = (const float*)d_in[2];
    const float* w_offm = (const float*)d_in[3];
    const float* b_offm = (const float*)d_in[4];
    const float* w_sk   = (const float*)d_in[5];
    const float* b_sk   = (const float*)d_in[6];
    const float* w_km   = (const float*)d_in[7];
    const float* b_km   = (const float*)d_in[8];
    float* outp = (float*)d_out;

    const size_t off_bytes = (size_t)Bc * 16 * HW * sizeof(__half2); // 4 MiB
    const size_t wt_bytes  = 2 * Cc * 32 * sizeof(float);            // 16 KiB
    if (ws_size < off_bytes + wt_bytes) return;
    __half2* offbuf = (__half2*)d_ws;
    float*   wT     = (float*)((char*)d_ws + off_bytes);

    dim3 blk(256);
    hipLaunchKernelGGL(kT_transpose, dim3(16), blk, 0, stream,
                       w_off, w_offm, wT);

    dim3 g0(HW / 128, Bc);                // (128, 4): 128 px x 2 roles
    hipLaunchKernelGGL(k0_offsets, g0, blk, 0, stream,
                       x, wT, b_off, b_offm, offbuf);

    dim3 g1(512, Bc);                     // 16x8 output tiles x b — NO swizzle
    hipLaunchKernelGGL(k1_fused, g1, blk, 0, stream,
                       x, offbuf, w_sk, b_sk, w_km, b_km, outp);
}

// Round 8
// 68.261 us; speedup vs baseline: 1.5486x; 1.5486x over previous
//
#include <hip/hip_runtime.h>
#include <hip/hip_fp16.h>

typedef _Float16 h2 __attribute__((ext_vector_type(2)));

constexpr int Bc  = 4;
constexpr int Cc  = 64;
constexpr int H0  = 128;
constexpr int W0  = 128;
constexpr int HW  = H0 * W0;
constexpr int Gc  = 4;
constexpr int HOc = H0 * 2;      // 256
constexpr int WOc = W0 * 2;      // 256

constexpr int TW = 16;           // output tile width
constexpr int TH = 8;            // output tile height
constexpr int HX = TW + 2;       // 18 halo cols
constexpr int HY = TH + 2;       // 10 halo rows
constexpr int NHALO = HX * HY;   // 180
constexpr int NTASK = Gc * NHALO;// 720

constexpr int SXC = 10;          // staged input cols (ox/2-1 .. ox/2+8)
constexpr int SYC = 6;           // staged input rows (oy/2-1 .. oy/2+4)
constexpr int SN  = SXC * SYC;   // 60 positions per channel
constexpr int NPAIR = Cc / 2;    // 32 channel pairs

__device__ __forceinline__ float dot2(h2 a, unsigned bw, float c) {
    union { unsigned u; h2 h; } cv; cv.u = bw;
#if __has_builtin(__builtin_amdgcn_fdot2)
    return __builtin_amdgcn_fdot2(a, cv.h, c, false);
#else
    return fmaf((float)a[0], (float)cv.h[0],
                fmaf((float)a[1], (float)cv.h[1], c));
#endif
}

// ---------------------------------------------------------------------------
// kT: prep weights in ws. wT[mat][c][r] (4096 f32) for k0;
// packed half2 w_sk/w_km [9][32 pairs] (576 u32) for k1 phase C.
// ---------------------------------------------------------------------------
__global__ __launch_bounds__(256) void kT_prep(
    const float* __restrict__ w_off, const float* __restrict__ w_offm,
    const float* __restrict__ w_sk,  const float* __restrict__ w_km,
    float* __restrict__ wT, __half2* __restrict__ wpk)
{
    const int i = blockIdx.x * 256 + threadIdx.x;
    if (i < 4096) {
        const int mat = i >> 11;
        const int rem = i & 2047;
        const int c   = rem >> 5;
        const int r   = rem & 31;
        wT[i] = (mat ? w_offm : w_off)[r * Cc + c];
    } else if (i < 4096 + 576) {
        const int j   = i - 4096;
        const int mat = j >= 288;
        const int jj  = mat ? j - 288 : j;
        const int k   = jj >> 5;
        const int c2  = jj & 31;
        const float* src = mat ? w_km : w_sk;
        wpk[j] = __floats2half2_rn(src[k * Cc + 2 * c2],
                                   src[k * Cc + 2 * c2 + 1]);
    }
}

// ---------------------------------------------------------------------------
// k0 v5: gated offset conv. Thread = 1 pixel x 16 rows x both matrices.
// r0 = (wave&1)*16 forced scalar via readfirstlane -> true s_load weight path.
// Output: half2 (offx,offy) per (b, pair, pixel), 4 MB total.
// ---------------------------------------------------------------------------
__global__ __launch_bounds__(256) void k0_offsets(
    const float* __restrict__ x, const float* __restrict__ wT,
    const float* __restrict__ b_off, const float* __restrict__ b_offm,
    __half2* __restrict__ offbuf)
{
    const int b    = blockIdx.y;
    const int t    = threadIdx.x;
    const int wave = t >> 6, lane = t & 63;
    const int r0   = __builtin_amdgcn_readfirstlane((wave & 1) * 16);
    const int px   = blockIdx.x * 128 + (wave >> 1) * 64 + lane;

    float a[16], m[16];
#pragma unroll
    for (int q = 0; q < 16; ++q) { a[q] = 0.f; m[q] = 0.f; }

    const float* xp  = x + (size_t)b * Cc * HW + px;
    const float* w0p = wT + r0;          // wT[0][c][r0..r0+15], stride 32
    const float* w1p = wT + 2048 + r0;   // wT[1][c][r0..r0+15]

#pragma unroll 2
    for (int c = 0; c < Cc; ++c) {
        const float xv = xp[c * HW];     // coalesced; L2-hot
#pragma unroll
        for (int q = 0; q < 16; ++q) {
            a[q] = fmaf(w0p[c * 32 + q], xv, a[q]);   // uniform -> s_load
            m[q] = fmaf(w1p[c * 32 + q], xv, m[q]);
        }
    }

#pragma unroll
    for (int j = 0; j < 8; ++j) {
        const int r = r0 + 2 * j;
        const float sx = 1.f / (1.f + __expf(-(m[2 * j]     + b_offm[r])));
        const float sy = 1.f / (1.f + __expf(-(m[2 * j + 1] + b_offm[r + 1])));
        const float vx = (a[2 * j]     + b_off[r])     * sx;
        const float vy = (a[2 * j + 1] + b_off[r + 1]) * sy;
        offbuf[((size_t)b * 16 + (r >> 1)) * HW + px] = __floats2half2_rn(vx, vy);
    }
}

// ---------------------------------------------------------------------------
// k1_fused: channel-pair half2 layout throughout. Phase B: pk bilinear.
// Phase C: reg-cached xv + fdot2 with packed uniform weights. Phase D: pk conv.
// LDS 32256 B -> 5 blocks/CU. No swizzle, default bounds.
// ---------------------------------------------------------------------------
__global__ __launch_bounds__(256) void k1_fused(
    const float* __restrict__ x, const __half2* __restrict__ offbuf,
    const unsigned* __restrict__ wsku, const float* __restrict__ b_sk,
    const float* __restrict__ b_km,
    float* __restrict__ out)
{
    __shared__ h2    xd2[NPAIR][NHALO];   // 23040 B: deformed halo, ch-pairs
    __shared__ float ovl[2304];           //  9216 B: xstage2 | kmb,sknb
    h2*       xstage2 = (h2*)ovl;         // [32 pairs][60]
    float*    kmb     = ovl;              // [128][9] f32
    unsigned* sknb    = (unsigned*)(ovl + 128 * 9); // [128][9] splat h2

    const unsigned* wkmu = wsku + 288;

    const int b    = blockIdx.y;
    const int tile = blockIdx.x;
    const int ox = (tile & 15) * TW;
    const int oy = (tile >> 4) * TH;
    const int t  = threadIdx.x;
    const int syr = (oy >> 1) - 1;
    const int sxr = (ox >> 1) - 1;

    const float* xb = x + (size_t)b * Cc * HW;

    // ---- phase A: stage 6x10 window as channel-pair half2 ----
    for (int i = t; i < NPAIR * SN; i += 256) {       // 1920 entries
        const int c2  = i / SN;
        const int rem = i - c2 * SN;
        const int r   = rem / SXC;
        const int j   = rem - r * SXC;
        const int yy  = min(max(syr + r, 0), H0 - 1);
        const int xx  = min(max(sxr + j, 0), W0 - 1);
        const float f0 = xb[(size_t)(2 * c2)     * HW + yy * W0 + xx];
        const float f1 = xb[(size_t)(2 * c2 + 1) * HW + yy * W0 + xx];
        xstage2[i] = h2{(_Float16)f0, (_Float16)f1};
    }
    __syncthreads();

    // ---- phase B: pk bilinear -> xd2 ----
    for (int task = t; task < NTASK; task += 256) {
        const int g   = task / NHALO;
        const int pix = task - g * NHALO;
        const int hy  = pix / HX;
        const int hx  = pix - hy * HX;
        const int gy  = oy - 1 + hy;
        const int gx  = ox - 1 + hx;
        if (gy < 0 || gy >= HOc || gx < 0 || gx >= WOc) {
#pragma unroll
            for (int p = 0; p < 8; ++p) xd2[g * 8 + p][pix] = (h2)0;
            continue;
        }
        const int sy = gy & 1, sx = gx & 1;
        const int h  = gy >> 1, w  = gx >> 1;
        const __half2 o2 = offbuf[((size_t)b * 16 + g * 4 + sy * 2 + sx) * HW
                                  + h * W0 + w];
        const float offx = __low2float(o2);
        const float offy = __high2float(o2);

        float ix = ((float)gx + 0.5f + offx) * 0.5f - 0.5f;
        float iy = ((float)gy + 0.5f + offy) * 0.5f - 0.5f;
        ix = fminf(fmaxf(ix, 0.f), (float)(W0 - 1));
        iy = fminf(fmaxf(iy, 0.f), (float)(H0 - 1));
        const float x0f = floorf(ix), y0f = floorf(iy);
        const float wx = ix - x0f,   wy = iy - y0f;
        const int x0 = (int)x0f, y0 = (int)y0f;
        const int x1 = min(x0 + 1, W0 - 1), y1 = min(y0 + 1, H0 - 1);
        const float w00 = (1.f - wx) * (1.f - wy);
        const float w01 = wx * (1.f - wy);
        const float w10 = (1.f - wx) * wy;
        const float w11 = wx * wy;

        const int j0 = x0 - sxr, j1 = x1 - sxr;
        const int i0 = y0 - syr, i1 = y1 - syr;
        const bool inl = (j0 >= 0) & (j1 < SXC) & (i0 >= 0) & (i1 < SYC);

        if (inl) {
            const int o00 = i0 * SXC + j0, o01 = i0 * SXC + j1;
            const int o10 = i1 * SXC + j0, o11 = i1 * SXC + j1;
            const _Float16 W00 = (_Float16)w00, W01 = (_Float16)w01;
            const _Float16 W10 = (_Float16)w10, W11 = (_Float16)w11;
            const h2* s2 = xstage2 + (g * 8) * SN;
#pragma unroll
            for (int p = 0; p < 8; ++p) {
                const h2* pc = s2 + p * SN;
                xd2[g * 8 + p][pix] =
                    pc[o00] * W00 + pc[o01] * W01 + pc[o10] * W10 + pc[o11] * W11;
            }
        } else {  // rare: tap escaped staged window -> global f32
            const int o00 = y0 * W0 + x0, o01 = y0 * W0 + x1;
            const int o10 = y1 * W0 + x0, o11 = y1 * W0 + x1;
#pragma unroll
            for (int p = 0; p < 8; ++p) {
                const float* pc0 = xb + (size_t)(g * 16 + 2 * p) * HW;
                const float* pc1 = pc0 + HW;
                const float v0 = w00 * pc0[o00] + w01 * pc0[o01]
                               + w10 * pc0[o10] + w11 * pc0[o11];
                const float v1 = w00 * pc1[o00] + w01 * pc1[o01]
                               + w10 * pc1[o10] + w11 * pc1[o11];
                xd2[g * 8 + p][pix] = h2{(_Float16)v0, (_Float16)v1};
            }
        }
    }
    __syncthreads();

    // ---- phase C: reg-cached xv + fdot2, gate + softmax -> sknb (splat h2) --
    {
        const int p   = t & 127;
        const int ctr = ((p >> 4) + 1) * HX + (p & 15) + 1;
        h2 xv[NPAIR];
#pragma unroll
        for (int c2 = 0; c2 < NPAIR; ++c2) xv[c2] = xd2[c2][ctr];

        float acc[9];
        if (t < 128) {
#pragma unroll
            for (int k = 0; k < 9; ++k) {
                float a = 0.f;
#pragma unroll
                for (int c2 = 0; c2 < NPAIR; ++c2)
                    a = dot2(xv[c2], wsku[k * 32 + c2], a);   // uniform s_load
                acc[k] = a;
            }
        } else {
#pragma unroll
            for (int k = 0; k < 9; ++k) {
                float a = 0.f;
#pragma unroll
                for (int c2 = 0; c2 < NPAIR; ++c2)
                    a = dot2(xv[c2], wkmu[k * 32 + c2], a);
                kmb[p * 9 + k] = a;
            }
        }
        __syncthreads();

        if (t < 128) {
            float sv[9], mx = -1e30f;
#pragma unroll
            for (int k = 0; k < 9; ++k) {
                const float z = kmb[p * 9 + k] + b_km[k];
                sv[k] = (acc[k] + b_sk[k]) / (1.f + __expf(-z));
                mx = fmaxf(mx, sv[k]);
            }
            float sum = 0.f;
#pragma unroll
            for (int k = 0; k < 9; ++k) { sv[k] = __expf(sv[k] - mx); sum += sv[k]; }
            const float inv = 1.f / sum;
#pragma unroll
            for (int k = 0; k < 9; ++k) {
                const unsigned hu = __half_as_ushort(__float2half(sv[k] * inv));
                sknb[p * 9 + k] = hu | (hu << 16);            // splat h2
            }
        }
    }
    __syncthreads();

    // ---- phase D: 3x3 dynamic conv, pk math, 2x2 px x 4 ch-pairs / thread --
    {
        const int sq    = t & 31;
        const int chunk = t >> 5;          // 8 chunks x 4 pairs
        const int sqx = sq & 7, sqy = sq >> 3;
        const int hx0 = 2 * sqx, hy0 = 2 * sqy;
        const int p00 = (2 * sqy) * TW + 2 * sqx;

        union { unsigned u; h2 h; } s00[9], s01[9], s10[9], s11[9];
#pragma unroll
        for (int k = 0; k < 9; ++k) {
            s00[k].u = sknb[p00 * 9 + k];        s01[k].u = sknb[(p00 + 1) * 9 + k];
            s10[k].u = sknb[(p00 + TW) * 9 + k]; s11[k].u = sknb[(p00 + TW + 1) * 9 + k];
        }
        const int orow0 = oy + 2 * sqy, ocol0 = ox + 2 * sqx;

#pragma unroll
        for (int i = 0; i < 4; ++i) {
            const int pr = chunk * 4 + i;
            h2 wd[4][4];
#pragma unroll
            for (int ry = 0; ry < 4; ++ry) {
                const int base = (hy0 + ry) * HX + hx0;
#pragma unroll
                for (int rx = 0; rx < 4; ++rx)
                    wd[ry][rx] = xd2[pr][base + rx];
            }
            h2 a00 = (h2)0, a01 = (h2)0, a10 = (h2)0, a11 = (h2)0;
#pragma unroll
            for (int ky = 0; ky < 3; ++ky)
#pragma unroll
                for (int kx = 0; kx < 3; ++kx) {
                    const int k = ky * 3 + kx;
                    a00 += s00[k].h * wd[ky    ][kx    ];
                    a01 += s01[k].h * wd[ky    ][kx + 1];
                    a10 += s10[k].h * wd[ky + 1][kx    ];
                    a11 += s11[k].h * wd[ky + 1][kx + 1];
                }
            float* ob0 = out + ((size_t)(b * Cc + 2 * pr)) * (HOc * WOc)
                             + (size_t)orow0 * WOc + ocol0;
            float* ob1 = ob0 + (size_t)(HOc * WOc);
            *reinterpret_cast<float2*>(ob0)       = make_float2((float)a00[0], (float)a01[0]);
            *reinterpret_cast<float2*>(ob0 + WOc) = make_float2((float)a10[0], (float)a11[0]);
            *reinterpret_cast<float2*>(ob1)       = make_float2((float)a00[1], (float)a01[1]);
            *reinterpret_cast<float2*>(ob1 + WOc) = make_float2((float)a10[1], (float)a11[1]);
        }
    }
}

// ---------------------------------------------------------------------------
extern "C" void kernel_launch(void* const* d_in, const int* in_sizes, int n_in,
                              void* d_out, int out_size, void* d_ws, size_t ws_size,
                              hipStream_t stream)
{
    const float* x      = (const float*)d_in[0];
    const float* w_off  = (const float*)d_in[1];
    const float* b_off  = (const float*)d_in[2];
    const float* w_offm = (const float*)d_in[3];
    const float* b_offm = (const float*)d_in[4];
    const float* w_sk   = (const float*)d_in[5];
    const float* b_sk   = (const float*)d_in[6];
    const float* w_km   = (const float*)d_in[7];
    const float* b_km   = (const float*)d_in[8];
    float* outp = (float*)d_out;

    const size_t off_bytes = (size_t)Bc * 16 * HW * sizeof(__half2); // 4 MiB
    const size_t wt_bytes  = 4096 * sizeof(float);                   // 16 KiB
    const size_t pk_bytes  = 576 * sizeof(__half2);
    if (ws_size < off_bytes + wt_bytes + pk_bytes) return;
    __half2* offbuf = (__half2*)d_ws;
    float*   wT     = (float*)((char*)d_ws + off_bytes);
    __half2* wpk    = (__half2*)((char*)d_ws + off_bytes + wt_bytes);

    dim3 blk(256);
    hipLaunchKernelGGL(kT_prep, dim3(19), blk, 0, stream,
                       w_off, w_offm, w_sk, w_km, wT, wpk);

    dim3 g0(HW / 128, Bc);                // 128 px per block
    hipLaunchKernelGGL(k0_offsets, g0, blk, 0, stream,
                       x, wT, b_off, b_offm, offbuf);

    dim3 g1(512, Bc);                     // 16x8 tiles x b — NO swizzle
    hipLaunchKernelGGL(k1_fused, g1, blk, 0, stream,
                       x, offbuf, (const unsigned*)wpk, b_sk, b_km, outp);
}

// Round 9
// 60.713 us; speedup vs baseline: 1.7411x; 1.1243x over previous
//
#include <hip/hip_runtime.h>
#include <hip/hip_fp16.h>

typedef _Float16 h2 __attribute__((ext_vector_type(2)));

constexpr int Bc  = 4;
constexpr int Cc  = 64;
constexpr int H0  = 128;
constexpr int W0  = 128;
constexpr int HW  = H0 * W0;
constexpr int Gc  = 4;
constexpr int HOc = H0 * 2;      // 256
constexpr int WOc = W0 * 2;      // 256

constexpr int TW = 16;           // output tile width
constexpr int TH = 8;            // output tile height
constexpr int HX = TW + 2;       // 18 halo cols
constexpr int HY = TH + 2;       // 10 halo rows
constexpr int NHALO = HX * HY;   // 180
constexpr int NTASK = Gc * NHALO;// 720

constexpr int SXC = 10;          // staged input cols (ox/2-1 .. ox/2+8)
constexpr int SYC = 6;           // staged input rows (oy/2-1 .. oy/2+4)
constexpr int SN  = SXC * SYC;   // 60 positions per channel
constexpr int NPAIR = Cc / 2;    // 32 channel pairs

union hu32 { unsigned u; h2 h; };

__device__ __forceinline__ float dot2(h2 a, unsigned bw, float c) {
    hu32 cv; cv.u = bw;
#if __has_builtin(__builtin_amdgcn_fdot2)
    return __builtin_amdgcn_fdot2(a, cv.h, c, false);
#else
    return fmaf((float)a[0], (float)cv.h[0],
                fmaf((float)a[1], (float)cv.h[1], c));
#endif
}

// ---------------------------------------------------------------------------
// kT: prep packed weights in ws.
// wpk0[c2*64 + mat*32 + r] = half2(src[r][2c2], src[r][2c2+1])  (2048 u32)
// wpk  [mat*288 + k*32 + c2] likewise for w_sk/w_km              (576 u32)
// ---------------------------------------------------------------------------
__global__ __launch_bounds__(256) void kT_prep(
    const float* __restrict__ w_off, const float* __restrict__ w_offm,
    const float* __restrict__ w_sk,  const float* __restrict__ w_km,
    __half2* __restrict__ wpk0, __half2* __restrict__ wpk)
{
    const int i = blockIdx.x * 256 + threadIdx.x;
    if (i < 2048) {
        const int c2  = i >> 6;
        const int rem = i & 63;
        const int mat = rem >> 5;
        const int r   = rem & 31;
        const float* src = mat ? w_offm : w_off;
        wpk0[i] = __floats2half2_rn(src[r * Cc + 2 * c2],
                                    src[r * Cc + 2 * c2 + 1]);
    } else if (i < 2048 + 576) {
        const int j   = i - 2048;
        const int mat = j >= 288;
        const int jj  = mat ? j - 288 : j;
        const int k   = jj >> 5;
        const int c2  = jj & 31;
        const float* src = mat ? w_km : w_sk;
        wpk[j] = __floats2half2_rn(src[k * Cc + 2 * c2],
                                   src[k * Cc + 2 * c2 + 1]);
    }
}

// ---------------------------------------------------------------------------
// k0 v6: gated offset conv + x transpose. Block = 64 px x 4 row-split waves.
// Wave w computes rows [w*8, w*8+8) of BOTH matrices via fdot2 with
// wave-uniform packed weights (s_load). Wave 0 also emits x_t fp16 [px][c].
// offbuf pixel-major: [b][px][16] half2 (offx,offy).
// Grid 1024 blocks -> 4 waves/SIMD latency hiding.
// ---------------------------------------------------------------------------
__global__ __launch_bounds__(256) void k0_offsets(
    const float* __restrict__ x, const unsigned* __restrict__ wpk0,
    const float* __restrict__ b_off, const float* __restrict__ b_offm,
    __half2* __restrict__ offbuf, unsigned* __restrict__ xt)
{
    const int b    = blockIdx.y;
    const int t    = threadIdx.x;
    const int wave = t >> 6, lane = t & 63;
    const int r0   = __builtin_amdgcn_readfirstlane(wave * 8);
    const int px   = blockIdx.x * 64 + lane;

    float a[8], m[8];
#pragma unroll
    for (int q = 0; q < 8; ++q) { a[q] = 0.f; m[q] = 0.f; }
    unsigned xtr[NPAIR];

    const float*    xp = x + (size_t)b * Cc * HW + px;
    const unsigned* wp = wpk0 + r0;      // wave-uniform base

#pragma unroll 4
    for (int c2 = 0; c2 < NPAIR; ++c2) {
        const float x0 = xp[(2 * c2)     * HW];   // coalesced 256B
        const float x1 = xp[(2 * c2 + 1) * HW];
        hu32 xh; xh.h = h2{(_Float16)x0, (_Float16)x1};
        xtr[c2] = xh.u;
#pragma unroll
        for (int q = 0; q < 8; ++q) {
            a[q] = dot2(xh.h, wp[c2 * 64 + q],      a[q]);  // s_load weights
            m[q] = dot2(xh.h, wp[c2 * 64 + 32 + q], m[q]);
        }
    }

    __half2* ob = offbuf + ((size_t)b * HW + px) * 16 + (r0 >> 1);
#pragma unroll
    for (int j = 0; j < 4; ++j) {
        const int r = r0 + 2 * j;
        const float sx = 1.f / (1.f + __expf(-(m[2 * j]     + b_offm[r])));
        const float sy = 1.f / (1.f + __expf(-(m[2 * j + 1] + b_offm[r + 1])));
        const float vx = (a[2 * j]     + b_off[r])     * sx;
        const float vy = (a[2 * j + 1] + b_off[r + 1]) * sy;
        ob[j] = __floats2half2_rn(vx, vy);        // dwordx4-merged
    }

    if (wave == 0) {                              // emit x_t fp16 [px][c]
        unsigned* xo = xt + ((size_t)b * HW + px) * NPAIR;
#pragma unroll
        for (int c2 = 0; c2 < NPAIR; ++c2) xo[c2] = xtr[c2];
    }
}

// ---------------------------------------------------------------------------
// k1_fused: phase A reads pixel-major x_t (128B bursts, zero line waste);
// phase B reads pixel-major offbuf (one line per (h,w), 16-task reuse);
// phases C/D as round 8 (fdot2 + pk conv). LDS 32256 B -> 5 blocks/CU.
// ---------------------------------------------------------------------------
__global__ __launch_bounds__(256) void k1_fused(
    const unsigned* __restrict__ xt, const __half2* __restrict__ offbuf,
    const unsigned* __restrict__ wsku, const float* __restrict__ b_sk,
    const float* __restrict__ b_km,
    float* __restrict__ out)
{
    __shared__ h2    xd2[NPAIR][NHALO];   // 23040 B: deformed halo, ch-pairs
    __shared__ float ovl[2304];           //  9216 B: xstage2 | kmb,sknb
    h2*       xstage2 = (h2*)ovl;         // [32 pairs][60]
    float*    kmb     = ovl;              // [128][9] f32
    unsigned* sknb    = (unsigned*)(ovl + 128 * 9); // [128][9] splat h2

    const unsigned* wkmu = wsku + 288;

    const int b    = blockIdx.y;
    const int tile = blockIdx.x;
    const int ox = (tile & 15) * TW;
    const int oy = (tile >> 4) * TH;
    const int t  = threadIdx.x;
    const int syr = (oy >> 1) - 1;
    const int sxr = (ox >> 1) - 1;

    const unsigned* xtb = xt + (size_t)b * HW * NPAIR;
    const __half2*  obb = offbuf + (size_t)b * HW * 16;

    // ---- phase A: stage 6x10 window from x_t (pixel-major, coalesced) ----
    unsigned* xs_u = (unsigned*)xstage2;
    for (int i = t; i < NPAIR * SN; i += 256) {       // 1920 u32
        const int c2  = i & 31;
        const int pos = i >> 5;
        const int r   = pos / SXC;
        const int j   = pos - r * SXC;
        const int yy  = min(max(syr + r, 0), H0 - 1);
        const int xx  = min(max(sxr + j, 0), W0 - 1);
        xs_u[c2 * SN + pos] = xtb[(yy * W0 + xx) * NPAIR + c2];
    }
    __syncthreads();

    // ---- phase B: pk bilinear -> xd2, offsets from pixel-major offbuf ----
    for (int task = t; task < NTASK; task += 256) {
        const int g   = task / NHALO;
        const int pix = task - g * NHALO;
        const int hy  = pix / HX;
        const int hx  = pix - hy * HX;
        const int gy  = oy - 1 + hy;
        const int gx  = ox - 1 + hx;
        if (gy < 0 || gy >= HOc || gx < 0 || gx >= WOc) {
#pragma unroll
            for (int p = 0; p < 8; ++p) xd2[g * 8 + p][pix] = (h2)0;
            continue;
        }
        const int sy = gy & 1, sx = gx & 1;
        const int h  = gy >> 1, w  = gx >> 1;
        const __half2 o2 = obb[(size_t)(h * W0 + w) * 16 + g * 4 + sy * 2 + sx];
        const float offx = __low2float(o2);
        const float offy = __high2float(o2);

        float ix = ((float)gx + 0.5f + offx) * 0.5f - 0.5f;
        float iy = ((float)gy + 0.5f + offy) * 0.5f - 0.5f;
        ix = fminf(fmaxf(ix, 0.f), (float)(W0 - 1));
        iy = fminf(fmaxf(iy, 0.f), (float)(H0 - 1));
        const float x0f = floorf(ix), y0f = floorf(iy);
        const float wx = ix - x0f,   wy = iy - y0f;
        const int x0 = (int)x0f, y0 = (int)y0f;
        const int x1 = min(x0 + 1, W0 - 1), y1 = min(y0 + 1, H0 - 1);
        const float w00 = (1.f - wx) * (1.f - wy);
        const float w01 = wx * (1.f - wy);
        const float w10 = (1.f - wx) * wy;
        const float w11 = wx * wy;

        const int j0 = x0 - sxr, j1 = x1 - sxr;
        const int i0 = y0 - syr, i1 = y1 - syr;
        const bool inl = (j0 >= 0) & (j1 < SXC) & (i0 >= 0) & (i1 < SYC);

        const _Float16 W00 = (_Float16)w00, W01 = (_Float16)w01;
        const _Float16 W10 = (_Float16)w10, W11 = (_Float16)w11;

        if (inl) {
            const int o00 = i0 * SXC + j0, o01 = i0 * SXC + j1;
            const int o10 = i1 * SXC + j0, o11 = i1 * SXC + j1;
            const h2* s2 = xstage2 + (g * 8) * SN;
#pragma unroll
            for (int p = 0; p < 8; ++p) {
                const h2* pc = s2 + p * SN;
                xd2[g * 8 + p][pix] =
                    pc[o00] * W00 + pc[o01] * W01 + pc[o10] * W10 + pc[o11] * W11;
            }
        } else {  // rare: tap escaped staged window -> global x_t
            const int o00 = (y0 * W0 + x0) * NPAIR, o01 = (y0 * W0 + x1) * NPAIR;
            const int o10 = (y1 * W0 + x0) * NPAIR, o11 = (y1 * W0 + x1) * NPAIR;
#pragma unroll
            for (int p = 0; p < 8; ++p) {
                const int c2 = g * 8 + p;
                hu32 v00, v01, v10, v11;
                v00.u = xtb[o00 + c2]; v01.u = xtb[o01 + c2];
                v10.u = xtb[o10 + c2]; v11.u = xtb[o11 + c2];
                xd2[c2][pix] =
                    v00.h * W00 + v01.h * W01 + v10.h * W10 + v11.h * W11;
            }
        }
    }
    __syncthreads();

    // ---- phase C: reg-cached xv + fdot2, gate + softmax -> sknb ----
    {
        const int p   = t & 127;
        const int ctr = ((p >> 4) + 1) * HX + (p & 15) + 1;
        h2 xv[NPAIR];
#pragma unroll
        for (int c2 = 0; c2 < NPAIR; ++c2) xv[c2] = xd2[c2][ctr];

        float acc[9];
        if (t < 128) {
#pragma unroll
            for (int k = 0; k < 9; ++k) {
                float a = 0.f;
#pragma unroll
                for (int c2 = 0; c2 < NPAIR; ++c2)
                    a = dot2(xv[c2], wsku[k * 32 + c2], a);   // uniform s_load
                acc[k] = a;
            }
        } else {
#pragma unroll
            for (int k = 0; k < 9; ++k) {
                float a = 0.f;
#pragma unroll
                for (int c2 = 0; c2 < NPAIR; ++c2)
                    a = dot2(xv[c2], wkmu[k * 32 + c2], a);
                kmb[p * 9 + k] = a;
            }
        }
        __syncthreads();

        if (t < 128) {
            float sv[9], mx = -1e30f;
#pragma unroll
            for (int k = 0; k < 9; ++k) {
                const float z = kmb[p * 9 + k] + b_km[k];
                sv[k] = (acc[k] + b_sk[k]) / (1.f + __expf(-z));
                mx = fmaxf(mx, sv[k]);
            }
            float sum = 0.f;
#pragma unroll
            for (int k = 0; k < 9; ++k) { sv[k] = __expf(sv[k] - mx); sum += sv[k]; }
            const float inv = 1.f / sum;
#pragma unroll
            for (int k = 0; k < 9; ++k) {
                const unsigned hu = __half_as_ushort(__float2half(sv[k] * inv));
                sknb[p * 9 + k] = hu | (hu << 16);            // splat h2
            }
        }
    }
    __syncthreads();

    // ---- phase D: 3x3 dynamic conv, pk math, 2x2 px x 4 ch-pairs / thread --
    {
        const int sq    = t & 31;
        const int chunk = t >> 5;          // 8 chunks x 4 pairs
        const int sqx = sq & 7, sqy = sq >> 3;
        const int hx0 = 2 * sqx, hy0 = 2 * sqy;
        const int p00 = (2 * sqy) * TW + 2 * sqx;

        hu32 s00[9], s01[9], s10[9], s11[9];
#pragma unroll
        for (int k = 0; k < 9; ++k) {
            s00[k].u = sknb[p00 * 9 + k];        s01[k].u = sknb[(p00 + 1) * 9 + k];
            s10[k].u = sknb[(p00 + TW) * 9 + k]; s11[k].u = sknb[(p00 + TW + 1) * 9 + k];
        }
        const int orow0 = oy + 2 * sqy, ocol0 = ox + 2 * sqx;

#pragma unroll
        for (int i = 0; i < 4; ++i) {
            const int pr = chunk * 4 + i;
            h2 wd[4][4];
#pragma unroll
            for (int ry = 0; ry < 4; ++ry) {
                const int base = (hy0 + ry) * HX + hx0;
#pragma unroll
                for (int rx = 0; rx < 4; ++rx)
                    wd[ry][rx] = xd2[pr][base + rx];
            }
            h2 a00 = (h2)0, a01 = (h2)0, a10 = (h2)0, a11 = (h2)0;
#pragma unroll
            for (int ky = 0; ky < 3; ++ky)
#pragma unroll
                for (int kx = 0; kx < 3; ++kx) {
                    const int k = ky * 3 + kx;
                    a00 += s00[k].h * wd[ky    ][kx    ];
                    a01 += s01[k].h * wd[ky    ][kx + 1];
                    a10 += s10[k].h * wd[ky + 1][kx    ];
                    a11 += s11[k].h * wd[ky + 1][kx + 1];
                }
            float* ob0 = out + ((size_t)(b * Cc + 2 * pr)) * (HOc * WOc)
                             + (size_t)orow0 * WOc + ocol0;
            float* ob1 = ob0 + (size_t)(HOc * WOc);
            *reinterpret_cast<float2*>(ob0)       = make_float2((float)a00[0], (float)a01[0]);
            *reinterpret_cast<float2*>(ob0 + WOc) = make_float2((float)a10[0], (float)a11[0]);
            *reinterpret_cast<float2*>(ob1)       = make_float2((float)a00[1], (float)a01[1]);
            *reinterpret_cast<float2*>(ob1 + WOc) = make_float2((float)a10[1], (float)a11[1]);
        }
    }
}

// ---------------------------------------------------------------------------
extern "C" void kernel_launch(void* const* d_in, const int* in_sizes, int n_in,
                              void* d_out, int out_size, void* d_ws, size_t ws_size,
                              hipStream_t stream)
{
    const float* x      = (const float*)d_in[0];
    const float* w_off  = (const float*)d_in[1];
    const float* b_off  = (const float*)d_in[2];
    const float* w_offm = (const float*)d_in[3];
    const float* b_offm = (const float*)d_in[4];
    const float* w_sk   = (const float*)d_in[5];
    const float* b_sk   = (const float*)d_in[6];
    const float* w_km   = (const float*)d_in[7];
    const float* b_km   = (const float*)d_in[8];
    float* outp = (float*)d_out;

    const size_t off_bytes  = (size_t)Bc * HW * 16 * sizeof(__half2); // 4 MiB
    const size_t xt_bytes   = (size_t)Bc * HW * NPAIR * sizeof(unsigned); // 8 MiB
    const size_t wpk0_bytes = 2048 * sizeof(__half2);
    const size_t wpk_bytes  = 576 * sizeof(__half2);
    if (ws_size < off_bytes + xt_bytes + wpk0_bytes + wpk_bytes) return;
    __half2*  offbuf = (__half2*)d_ws;
    unsigned* xtbuf  = (unsigned*)((char*)d_ws + off_bytes);
    __half2*  wpk0   = (__half2*)((char*)d_ws + off_bytes + xt_bytes);
    __half2*  wpk    = (__half2*)((char*)d_ws + off_bytes + xt_bytes + wpk0_bytes);

    dim3 blk(256);
    hipLaunchKernelGGL(kT_prep, dim3(11), blk, 0, stream,
                       w_off, w_offm, w_sk, w_km, wpk0, wpk);

    dim3 g0(HW / 64, Bc);                 // 1024 blocks: 64 px x 4 row-waves
    hipLaunchKernelGGL(k0_offsets, g0, blk, 0, stream,
                       x, (const unsigned*)wpk0, b_off, b_offm, offbuf, xtbuf);

    dim3 g1(512, Bc);                     // 16x8 tiles x b — NO swizzle
    hipLaunchKernelGGL(k1_fused, g1, blk, 0, stream,
                       xtbuf, offbuf, (const unsigned*)wpk, b_sk, b_km, outp);
}

// Round 10
// 55.426 us; speedup vs baseline: 1.9072x; 1.0954x over previous
//
#include <hip/hip_runtime.h>
#include <hip/hip_fp16.h>

typedef _Float16 h2 __attribute__((ext_vector_type(2)));

constexpr int Bc  = 4;
constexpr int Cc  = 64;
constexpr int H0  = 128;
constexpr int W0  = 128;
constexpr int HW  = H0 * W0;
constexpr int Gc  = 4;
constexpr int HOc = H0 * 2;      // 256
constexpr int WOc = W0 * 2;      // 256

constexpr int TW = 16;           // output tile width
constexpr int TH = 8;            // output tile height
constexpr int HX = TW + 2;       // 18 halo cols
constexpr int HY = TH + 2;       // 10 halo rows
constexpr int NHALO = HX * HY;   // 180
constexpr int NTASK = Gc * NHALO;// 720

constexpr int SXC = 10;          // staged input cols (ox/2-1 .. ox/2+8)
constexpr int SYC = 6;           // staged input rows (oy/2-1 .. oy/2+4)
constexpr int SN  = SXC * SYC;   // 60 positions per channel
constexpr int NPAIR = Cc / 2;    // 32 channel pairs
constexpr int NSTG  = NPAIR * SN;// 1920 u32 per tile stage

union hu32 { unsigned u; h2 h; };

__device__ __forceinline__ float dot2(h2 a, unsigned bw, float c) {
    hu32 cv; cv.u = bw;
#if __has_builtin(__builtin_amdgcn_fdot2)
    return __builtin_amdgcn_fdot2(a, cv.h, c, false);
#else
    return fmaf((float)a[0], (float)cv.h[0],
                fmaf((float)a[1], (float)cv.h[1], c));
#endif
}

// ---------------------------------------------------------------------------
// kT: prep packed weights in ws (unchanged from round 9).
// ---------------------------------------------------------------------------
__global__ __launch_bounds__(256) void kT_prep(
    const float* __restrict__ w_off, const float* __restrict__ w_offm,
    const float* __restrict__ w_sk,  const float* __restrict__ w_km,
    __half2* __restrict__ wpk0, __half2* __restrict__ wpk)
{
    const int i = blockIdx.x * 256 + threadIdx.x;
    if (i < 2048) {
        const int c2  = i >> 6;
        const int rem = i & 63;
        const int mat = rem >> 5;
        const int r   = rem & 31;
        const float* src = mat ? w_offm : w_off;
        wpk0[i] = __floats2half2_rn(src[r * Cc + 2 * c2],
                                    src[r * Cc + 2 * c2 + 1]);
    } else if (i < 2048 + 576) {
        const int j   = i - 2048;
        const int mat = j >= 288;
        const int jj  = mat ? j - 288 : j;
        const int k   = jj >> 5;
        const int c2  = jj & 31;
        const float* src = mat ? w_km : w_sk;
        wpk[j] = __floats2half2_rn(src[k * Cc + 2 * c2],
                                   src[k * Cc + 2 * c2 + 1]);
    }
}

// ---------------------------------------------------------------------------
// k0 v6 (unchanged from round 9): gated offset conv + x transpose.
// ---------------------------------------------------------------------------
__global__ __launch_bounds__(256) void k0_offsets(
    const float* __restrict__ x, const unsigned* __restrict__ wpk0,
    const float* __restrict__ b_off, const float* __restrict__ b_offm,
    __half2* __restrict__ offbuf, unsigned* __restrict__ xt)
{
    const int b    = blockIdx.y;
    const int t    = threadIdx.x;
    const int wave = t >> 6, lane = t & 63;
    const int r0   = __builtin_amdgcn_readfirstlane(wave * 8);
    const int px   = blockIdx.x * 64 + lane;

    float a[8], m[8];
#pragma unroll
    for (int q = 0; q < 8; ++q) { a[q] = 0.f; m[q] = 0.f; }
    unsigned xtr[NPAIR];

    const float*    xp = x + (size_t)b * Cc * HW + px;
    const unsigned* wp = wpk0 + r0;      // wave-uniform base

#pragma unroll 4
    for (int c2 = 0; c2 < NPAIR; ++c2) {
        const float x0 = xp[(2 * c2)     * HW];   // coalesced 256B
        const float x1 = xp[(2 * c2 + 1) * HW];
        hu32 xh; xh.h = h2{(_Float16)x0, (_Float16)x1};
        xtr[c2] = xh.u;
#pragma unroll
        for (int q = 0; q < 8; ++q) {
            a[q] = dot2(xh.h, wp[c2 * 64 + q],      a[q]);  // s_load weights
            m[q] = dot2(xh.h, wp[c2 * 64 + 32 + q], m[q]);
        }
    }

    __half2* ob = offbuf + ((size_t)b * HW + px) * 16 + (r0 >> 1);
#pragma unroll
    for (int j = 0; j < 4; ++j) {
        const int r = r0 + 2 * j;
        const float sx = 1.f / (1.f + __expf(-(m[2 * j]     + b_offm[r])));
        const float sy = 1.f / (1.f + __expf(-(m[2 * j + 1] + b_offm[r + 1])));
        const float vx = (a[2 * j]     + b_off[r])     * sx;
        const float vy = (a[2 * j + 1] + b_off[r + 1]) * sy;
        ob[j] = __floats2half2_rn(vx, vy);        // dwordx4-merged
    }

    if (wave == 0) {                              // emit x_t fp16 [px][c]
        unsigned* xo = xt + ((size_t)b * HW + px) * NPAIR;
#pragma unroll
        for (int c2 = 0; c2 < NPAIR; ++c2) xo[c2] = xtr[c2];
    }
}

// ---------------------------------------------------------------------------
// k1_fused v2: persistent 2-tile blocks (oy, oy+8) with cross-tile T14
// prefetch. Both tiles' stage loads issued in prologue; tile1's LDS write
// slots after B0's barrier (hidden under C0/D0). LDS 37632 B -> 4 blocks/CU;
// grid 1024 = 4 blocks/CU resident.
// ---------------------------------------------------------------------------
__global__ __launch_bounds__(256) void k1_fused(
    const unsigned* __restrict__ xt, const __half2* __restrict__ offbuf,
    const unsigned* __restrict__ wsku, const float* __restrict__ b_sk,
    const float* __restrict__ b_km,
    float* __restrict__ out)
{
    __shared__ h2       xd2[NPAIR][NHALO];   // 23040 B: deformed halo
    __shared__ unsigned xs_u[NSTG];          //  7680 B: stage (u32 = h2 pair)
    __shared__ unsigned short kmbh[128 * 9]; //  2304 B: km logits fp16
    __shared__ unsigned sknb[128 * 9];       //  4608 B: softmax splat h2

    const unsigned* wkmu = wsku + 288;

    const int b    = blockIdx.y;
    const int tp   = blockIdx.x;           // 16 x-tiles * 16 y-pairs
    const int ox = (tp & 15) * TW;
    const int oyb = (tp >> 4) * (2 * TH);  // y-pair base
    const int t  = threadIdx.x;
    const int sxr = (ox >> 1) - 1;
    const int syr0 = (oyb >> 1) - 1;       // tile0 window origin rows
    const int syr1 = syr0 + (TH >> 1);     // tile1: +4 rows

    const unsigned* xtb = xt + (size_t)b * HW * NPAIR;
    const __half2*  obb = offbuf + (size_t)b * HW * 16;

    // ---- prologue: issue BOTH tiles' stage loads into registers ----
    unsigned pre0[8], pre1[8];
#pragma unroll
    for (int k = 0; k < 8; ++k) {
        const int i = t + k * 256;
        if (i < NSTG) {
            const int c2  = i & 31;
            const int pos = i >> 5;
            const int r   = pos / SXC;
            const int j   = pos - r * SXC;
            const int xx  = min(max(sxr + j, 0), W0 - 1);
            const int yy0 = min(max(syr0 + r, 0), H0 - 1);
            const int yy1 = min(max(syr1 + r, 0), H0 - 1);
            pre0[k] = xtb[(yy0 * W0 + xx) * NPAIR + c2];
            pre1[k] = xtb[(yy1 * W0 + xx) * NPAIR + c2];
        }
    }
#pragma unroll
    for (int k = 0; k < 8; ++k) {
        const int i = t + k * 256;
        if (i < NSTG) {
            const int c2 = i & 31, pos = i >> 5;
            xs_u[c2 * SN + pos] = pre0[k];
        }
    }
    __syncthreads();

    for (int yt = 0; yt < 2; ++yt) {
        const int oy  = oyb + yt * TH;
        const int syr = yt ? syr1 : syr0;
        const h2* xstage2 = (const h2*)xs_u;

        // ---- phase B: pk bilinear -> xd2 ----
        for (int task = t; task < NTASK; task += 256) {
            const int g   = task / NHALO;
            const int pix = task - g * NHALO;
            const int hy  = pix / HX;
            const int hx  = pix - hy * HX;
            const int gy  = oy - 1 + hy;
            const int gx  = ox - 1 + hx;
            if (gy < 0 || gy >= HOc || gx < 0 || gx >= WOc) {
#pragma unroll
                for (int p = 0; p < 8; ++p) xd2[g * 8 + p][pix] = (h2)0;
                continue;
            }
            const int sy = gy & 1, sx = gx & 1;
            const int h  = gy >> 1, w  = gx >> 1;
            const __half2 o2 = obb[(size_t)(h * W0 + w) * 16 + g * 4 + sy * 2 + sx];
            const float offx = __low2float(o2);
            const float offy = __high2float(o2);

            float ix = ((float)gx + 0.5f + offx) * 0.5f - 0.5f;
            float iy = ((float)gy + 0.5f + offy) * 0.5f - 0.5f;
            ix = fminf(fmaxf(ix, 0.f), (float)(W0 - 1));
            iy = fminf(fmaxf(iy, 0.f), (float)(H0 - 1));
            const float x0f = floorf(ix), y0f = floorf(iy);
            const float wx = ix - x0f,   wy = iy - y0f;
            const int x0 = (int)x0f, y0 = (int)y0f;
            const int x1 = min(x0 + 1, W0 - 1), y1 = min(y0 + 1, H0 - 1);
            const float w00 = (1.f - wx) * (1.f - wy);
            const float w01 = wx * (1.f - wy);
            const float w10 = (1.f - wx) * wy;
            const float w11 = wx * wy;

            const int j0 = x0 - sxr, j1 = x1 - sxr;
            const int i0 = y0 - syr, i1 = y1 - syr;
            const bool inl = (j0 >= 0) & (j1 < SXC) & (i0 >= 0) & (i1 < SYC);

            const _Float16 W00 = (_Float16)w00, W01 = (_Float16)w01;
            const _Float16 W10 = (_Float16)w10, W11 = (_Float16)w11;

            if (inl) {
                const int o00 = i0 * SXC + j0, o01 = i0 * SXC + j1;
                const int o10 = i1 * SXC + j0, o11 = i1 * SXC + j1;
                const h2* s2 = xstage2 + (g * 8) * SN;
#pragma unroll
                for (int p = 0; p < 8; ++p) {
                    const h2* pc = s2 + p * SN;
                    xd2[g * 8 + p][pix] =
                        pc[o00] * W00 + pc[o01] * W01 + pc[o10] * W10 + pc[o11] * W11;
                }
            } else {  // rare: tap escaped staged window -> global x_t
                const int o00 = (y0 * W0 + x0) * NPAIR, o01 = (y0 * W0 + x1) * NPAIR;
                const int o10 = (y1 * W0 + x0) * NPAIR, o11 = (y1 * W0 + x1) * NPAIR;
#pragma unroll
                for (int p = 0; p < 8; ++p) {
                    const int c2 = g * 8 + p;
                    hu32 v00, v01, v10, v11;
                    v00.u = xtb[o00 + c2]; v01.u = xtb[o01 + c2];
                    v10.u = xtb[o10 + c2]; v11.u = xtb[o11 + c2];
                    xd2[c2][pix] =
                        v00.h * W00 + v01.h * W01 + v10.h * W10 + v11.h * W11;
                }
            }
        }
        __syncthreads();

        // ---- tile1 stage write: xstage is dead now; hide under C/D ----
        if (yt == 0) {
#pragma unroll
            for (int k = 0; k < 8; ++k) {
                const int i = t + k * 256;
                if (i < NSTG) {
                    const int c2 = i & 31, pos = i >> 5;
                    xs_u[c2 * SN + pos] = pre1[k];
                }
            }
        }

        // ---- phase C: reg-cached xv + fdot2, gate + softmax -> sknb ----
        {
            const int p   = t & 127;
            const int ctr = ((p >> 4) + 1) * HX + (p & 15) + 1;
            h2 xv[NPAIR];
#pragma unroll
            for (int c2 = 0; c2 < NPAIR; ++c2) xv[c2] = xd2[c2][ctr];

            float acc[9];
            if (t < 128) {
#pragma unroll
                for (int k = 0; k < 9; ++k) {
                    float a = 0.f;
#pragma unroll
                    for (int c2 = 0; c2 < NPAIR; ++c2)
                        a = dot2(xv[c2], wsku[k * 32 + c2], a);   // s_load
                    acc[k] = a;
                }
            } else {
#pragma unroll
                for (int k = 0; k < 9; ++k) {
                    float a = 0.f;
#pragma unroll
                    for (int c2 = 0; c2 < NPAIR; ++c2)
                        a = dot2(xv[c2], wkmu[k * 32 + c2], a);
                    kmbh[p * 9 + k] = __half_as_ushort(__float2half(a));
                }
            }
            __syncthreads();

            if (t < 128) {
                float sv[9], mx = -1e30f;
#pragma unroll
                for (int k = 0; k < 9; ++k) {
                    const float z = __half2float(__ushort_as_half(kmbh[p * 9 + k]))
                                    + b_km[k];
                    sv[k] = (acc[k] + b_sk[k]) / (1.f + __expf(-z));
                    mx = fmaxf(mx, sv[k]);
                }
                float sum = 0.f;
#pragma unroll
                for (int k = 0; k < 9; ++k) { sv[k] = __expf(sv[k] - mx); sum += sv[k]; }
                const float inv = 1.f / sum;
#pragma unroll
                for (int k = 0; k < 9; ++k) {
                    const unsigned hu = __half_as_ushort(__float2half(sv[k] * inv));
                    sknb[p * 9 + k] = hu | (hu << 16);            // splat h2
                }
            }
        }
        __syncthreads();

        // ---- phase D: 3x3 dynamic conv, pk math ----
        {
            const int sq    = t & 31;
            const int chunk = t >> 5;          // 8 chunks x 4 pairs
            const int sqx = sq & 7, sqy = sq >> 3;
            const int hx0 = 2 * sqx, hy0 = 2 * sqy;
            const int p00 = (2 * sqy) * TW + 2 * sqx;

            hu32 s00[9], s01[9], s10[9], s11[9];
#pragma unroll
            for (int k = 0; k < 9; ++k) {
                s00[k].u = sknb[p00 * 9 + k];        s01[k].u = sknb[(p00 + 1) * 9 + k];
                s10[k].u = sknb[(p00 + TW) * 9 + k]; s11[k].u = sknb[(p00 + TW + 1) * 9 + k];
            }
            const int orow0 = oy + 2 * sqy, ocol0 = ox + 2 * sqx;

#pragma unroll
            for (int i = 0; i < 4; ++i) {
                const int pr = chunk * 4 + i;
                h2 wd[4][4];
#pragma unroll
                for (int ry = 0; ry < 4; ++ry) {
                    const int base = (hy0 + ry) * HX + hx0;
#pragma unroll
                    for (int rx = 0; rx < 4; ++rx)
                        wd[ry][rx] = xd2[pr][base + rx];
                }
                h2 a00 = (h2)0, a01 = (h2)0, a10 = (h2)0, a11 = (h2)0;
#pragma unroll
                for (int ky = 0; ky < 3; ++ky)
#pragma unroll
                    for (int kx = 0; kx < 3; ++kx) {
                        const int k = ky * 3 + kx;
                        a00 += s00[k].h * wd[ky    ][kx    ];
                        a01 += s01[k].h * wd[ky    ][kx + 1];
                        a10 += s10[k].h * wd[ky + 1][kx    ];
                        a11 += s11[k].h * wd[ky + 1][kx + 1];
                    }
                float* ob0 = out + ((size_t)(b * Cc + 2 * pr)) * (HOc * WOc)
                                 + (size_t)orow0 * WOc + ocol0;
                float* ob1 = ob0 + (size_t)(HOc * WOc);
                *reinterpret_cast<float2*>(ob0)       = make_float2((float)a00[0], (float)a01[0]);
                *reinterpret_cast<float2*>(ob0 + WOc) = make_float2((float)a10[0], (float)a11[0]);
                *reinterpret_cast<float2*>(ob1)       = make_float2((float)a00[1], (float)a01[1]);
                *reinterpret_cast<float2*>(ob1 + WOc) = make_float2((float)a10[1], (float)a11[1]);
            }
        }
        __syncthreads();   // xd2/xstage WAR before next tile's phase B
    }
}

// ---------------------------------------------------------------------------
extern "C" void kernel_launch(void* const* d_in, const int* in_sizes, int n_in,
                              void* d_out, int out_size, void* d_ws, size_t ws_size,
                              hipStream_t stream)
{
    const float* x      = (const float*)d_in[0];
    const float* w_off  = (const float*)d_in[1];
    const float* b_off  = (const float*)d_in[2];
    const float* w_offm = (const float*)d_in[3];
    const float* b_offm = (const float*)d_in[4];
    const float* w_sk   = (const float*)d_in[5];
    const float* b_sk   = (const float*)d_in[6];
    const float* w_km   = (const float*)d_in[7];
    const float* b_km   = (const float*)d_in[8];
    float* outp = (float*)d_out;

    const size_t off_bytes  = (size_t)Bc * HW * 16 * sizeof(__half2);     // 4 MiB
    const size_t xt_bytes   = (size_t)Bc * HW * NPAIR * sizeof(unsigned); // 8 MiB
    const size_t wpk0_bytes = 2048 * sizeof(__half2);
    const size_t wpk_bytes  = 576 * sizeof(__half2);
    if (ws_size < off_bytes + xt_bytes + wpk0_bytes + wpk_bytes) return;
    __half2*  offbuf = (__half2*)d_ws;
    unsigned* xtbuf  = (unsigned*)((char*)d_ws + off_bytes);
    __half2*  wpk0   = (__half2*)((char*)d_ws + off_bytes + xt_bytes);
    __half2*  wpk    = (__half2*)((char*)d_ws + off_bytes + xt_bytes + wpk0_bytes);

    dim3 blk(256);
    hipLaunchKernelGGL(kT_prep, dim3(11), blk, 0, stream,
                       w_off, w_offm, w_sk, w_km, wpk0, wpk);

    dim3 g0(HW / 64, Bc);                 // 1024 blocks: 64 px x 4 row-waves
    hipLaunchKernelGGL(k0_offsets, g0, blk, 0, stream,
                       x, (const unsigned*)wpk0, b_off, b_offm, offbuf, xtbuf);

    dim3 g1(256, Bc);                     // 16x16 y-pair tiles x b — NO swizzle
    hipLaunchKernelGGL(k1_fused, g1, blk, 0, stream,
                       xtbuf, offbuf, (const unsigned*)wpk, b_sk, b_km, outp);
}